// Round 5
// baseline (756.761 us; speedup 1.0000x reference)
//
#include <hip/hip_runtime.h>
#include <hip/hip_bf16.h>
#include <cstdint>

// Problem constants (EnBaseLayer: E(n)-GNN layer)
#define NN 50000
#define NE 600000
#define HD 128
#define NG 20
#define EF 4
#define K1 280            // 2H + NG + EF
#define TILES (NE/64)     // 9375
#define EGRID 512         // 2 blocks/CU resident
#define ROWU 148          // s_inp row stride in u32 (592 B = 37*16)
#define NTILE 782         // ceil(NN/64)
// bank-conflict swizzle: permute 16B slots within each 8-row (128B) group
#define SW(r) ((r) ^ (((r)>>3)&7))

typedef __attribute__((ext_vector_type(4))) float f32x4;
typedef __attribute__((ext_vector_type(8))) __bf16 bf16x8;
typedef __attribute__((ext_vector_type(4))) unsigned int u32x4;

__device__ __forceinline__ float fast_rcp(float x){ return __builtin_amdgcn_rcpf(x); }
__device__ __forceinline__ float silu_f(float x){ return x * fast_rcp(1.0f + __expf(-x)); }
__device__ __forceinline__ float sigmoid_f(float x){ return fast_rcp(1.0f + __expf(-x)); }
__device__ __forceinline__ float tanh_f(float x){ return 1.0f - 2.0f*fast_rcp(__expf(2.0f*x)+1.0f); }

__device__ __forceinline__ uint32_t pk2(float a, float b){   // RNE f32x2 -> bf16x2
  uint32_t ua = __float_as_uint(a); ua += 0x7FFFu + ((ua>>16)&1u);
  uint32_t ub = __float_as_uint(b); ub += 0x7FFFu + ((ub>>16)&1u);
  return (ua>>16) | (ub & 0xFFFF0000u);
}
__device__ __forceinline__ uint16_t bfb(float a){
  uint32_t ua = __float_as_uint(a); ua += 0x7FFFu + ((ua>>16)&1u);
  return (uint16_t)(ua>>16);
}
__device__ __forceinline__ float bf2f(uint16_t b){ return __uint_as_float(((uint32_t)b)<<16); }
__device__ __forceinline__ f32x4 MF(u32x4 a, u32x4 b, f32x4 c){
  return __builtin_amdgcn_mfma_f32_16x16x32_bf16(
      __builtin_bit_cast(bf16x8, a), __builtin_bit_cast(bf16x8, b), c, 0, 0, 0);
}

#define EDGE_LDS_U32 (64*ROWU + 4096 + 4096 + 448)
#define EDGE_LDS_B (EDGE_LDS_U32*4)   // 72448 B -> 2 blocks/CU

// ---------------------------------------------------------------------------
// Edge kernel: 8 waves/block, tile = 64 edges, split-transit software pipeline.
// Wave w owns N-tile w (channels 16w..16w+15).
// A-frag: lane l holds row l&15, k = 32ks + 8*(l>>4) + j.
// D-frag: row(m)=4*(l>>4)+reg, col(n)=l&15.
// t1f/mf_ slot index XOR-swizzled (SW) for conflict-free LDS banks.
// Pipeline per tile t: [top sync] write geometry arrays(t), load indices(t+1)
//  [sync] GEMM1(t), issue h-round-A(t+1) [sync] GEMM2(t), pack+write A,
//  issue h-round-B(t+1) [sync] mi scatter + GEMM3(t), pack+write B,
//  geometry prefetch+gauss write(t+1) [sync] dx scatter(t).
// Transit state is <=16 f32 at any point -> fits the 128-reg budget (no spill).
// ---------------------------------------------------------------------------
__global__ void __launch_bounds__(512, 4) edge_kernel(
    const float* __restrict__ h, const float* __restrict__ x,
    const int* __restrict__ ei, const float* __restrict__ eattr,
    const float* __restrict__ We1, const float* __restrict__ be1,
    const float* __restrict__ We2, const float* __restrict__ be2,
    const float* __restrict__ Winf, const float* __restrict__ binf,
    const float* __restrict__ Wx1, const float* __restrict__ bx1,
    const float* __restrict__ Wx2, float* __restrict__ out)
{
  extern __shared__ uint32_t smem[];
  uint32_t* s_inp = smem;                                   // [64][ROWU]
  uint16_t* t1f   = (uint16_t*)(smem + 64*ROWU);            // [16][64][8] u16
  uint16_t* mf_   = (uint16_t*)(smem + 64*ROWU + 4096);     // [16][64][8] u16
  uint32_t* tl    = smem + 64*ROWU + 8192;
  int*   s_dst  = (int*)tl;            // 64
  float* s_rel  = (float*)(tl+64);     // 192
  float* s_dist = (float*)(tl+256);    // 64
  float* s_pe   = (float*)(tl+320);    // 64
  float* s_pg   = (float*)(tl+384);    // 64

  const int tid = threadIdx.x;
  const int w = tid >> 6, l = tid & 63;
  const int lo = l & 15, hi = l >> 4;
  const int col = w*16 + lo;
  const int r8 = tid >> 3, p8 = tid & 7;
  const int ks2 = w >> 1;
  const int lp  = ((w&1)*2 + (lo>>3))*16 + 4*hi;
  const int jj  = lo & 7;
  const int lsw = SW(l);

  // ---- persistent weight B-fragments (17 frags = 68 regs, land in AGPRs) ----
  u32x4 B1[9], B2[4], B3[4];
  #pragma unroll
  for (int ks = 0; ks < 9; ++ks){
    float f[8];
    #pragma unroll
    for (int j = 0; j < 8; ++j){
      const int k = ks*32 + hi*8 + j;
      f[j] = (k < K1) ? We1[k*HD + col] : 0.0f;
    }
    B1[ks] = {pk2(f[0],f[1]), pk2(f[2],f[3]), pk2(f[4],f[5]), pk2(f[6],f[7])};
  }
  #pragma unroll
  for (int ks = 0; ks < 4; ++ks){
    float f2[8], f3[8];
    #pragma unroll
    for (int j = 0; j < 8; ++j){
      const int k = ks*32 + hi*8 + j;
      f2[j] = We2[k*HD + col];
      f3[j] = Wx1[k*HD + col];
    }
    B2[ks] = {pk2(f2[0],f2[1]), pk2(f2[2],f2[3]), pk2(f2[4],f2[5]), pk2(f2[6],f2[7])};
    B3[ks] = {pk2(f3[0],f3[1]), pk2(f3[2],f3[3]), pk2(f3[4],f3[5]), pk2(f3[6],f3[7])};
  }
  const float vbe1 = be1[col], vbe2 = be2[col], vbx1 = bx1[col];
  const float wi = Winf[col], wx = Wx2[col], vbinf = binf[0];
  const float SP = 10.0f/19.0f;
  const float CO = -0.5f/(SP*SP);

  // cross-iteration pipeline state (small!)
  int pnode = 0;                     // h-row node for tile t+1 (this thread)
  int psj = 0, pdj = 0;              // tid<64: src/dst of tile t+1
  int   gdj = 0;                     // tid<64: dst of tile t (for array writes)
  float gr0=0, gr1=0, gr2=0, gdd=0;  // tid<64: rel/dist of tile t

  // ---- prologue: full staging of tile t0 (one-time stall) ----
  {
    const int ebase = blockIdx.x*64;
    const int e = ebase + r8;
    const int node0 = (p8 < 4) ? ei[NE+e] : ei[e];   // cols 0..127 = h[dst]
    const float* hp = h + (size_t)node0*HD + (p8&3)*32;
    uint32_t* dp = s_inp + r8*ROWU + p8*16;
    #pragma unroll
    for (int q = 0; q < 4; ++q){
      const float4 va = *reinterpret_cast<const float4*>(hp + 8*q);
      const float4 vb = *reinterpret_cast<const float4*>(hp + 8*q + 4);
      u32x4 v = { pk2(va.x,va.y), pk2(va.z,va.w), pk2(vb.x,vb.y), pk2(vb.z,vb.w) };
      *reinterpret_cast<u32x4*>(dp + 4*q) = v;
    }
    if (tid < 64){
      const int sj = ei[ebase+tid], dj = ei[NE+ebase+tid];
      const float ax = x[dj*3+0]-x[sj*3+0];
      const float ay = x[dj*3+1]-x[sj*3+1];
      const float az = x[dj*3+2]-x[sj*3+2];
      const float dd = sqrtf(ax*ax + ay*ay + az*az + 1e-8f);
      gdj = dj; gr0 = ax; gr1 = ay; gr2 = az; gdd = dd;
      float g[24];
      #pragma unroll
      for (int j = 0; j < 20; ++j){ const float a = dd - j*SP; g[j] = __expf(CO*a*a); }
      const float4 e4 = *reinterpret_cast<const float4*>(eattr + (size_t)(ebase+tid)*EF);
      g[20]=e4.x; g[21]=e4.y; g[22]=e4.z; g[23]=e4.w;
      uint32_t* gp = s_inp + tid*ROWU + 128;
      u32x4 g0v = {pk2(g[0],g[1]),  pk2(g[2],g[3]),  pk2(g[4],g[5]),  pk2(g[6],g[7])};
      u32x4 g1v = {pk2(g[8],g[9]),  pk2(g[10],g[11]),pk2(g[12],g[13]),pk2(g[14],g[15])};
      u32x4 g2v = {pk2(g[16],g[17]),pk2(g[18],g[19]),pk2(g[20],g[21]),pk2(g[22],g[23])};
      u32x4 g3v = {0,0,0,0};
      *reinterpret_cast<u32x4*>(gp)    = g0v;
      *reinterpret_cast<u32x4*>(gp+4)  = g1v;
      *reinterpret_cast<u32x4*>(gp+8)  = g2v;
      *reinterpret_cast<u32x4*>(gp+12) = g3v;   // pad columns, written once
    }
  }

  for (int t = blockIdx.x; t < TILES; t += EGRID){
    const bool more = (t + EGRID) < TILES;
    const int nbase = (t + EGRID)*64;
    float4 hA0, hA1, hA2, hA3;       // transit round A (16 f32)

    // (1) separate previous dx scatter from geometry array writes
    __syncthreads();

    // (2) geometry arrays for tile t + index prefetch for t+1
    if (tid < 64){
      s_dst[tid] = gdj;
      s_rel[3*tid+0]=gr0; s_rel[3*tid+1]=gr1; s_rel[3*tid+2]=gr2;
      s_dist[tid]=gdd; s_pe[tid]=0.0f; s_pg[tid]=0.0f;
    }
    if (more){
      const int e = nbase + r8;
      pnode = (p8 < 4) ? ei[NE+e] : ei[e];
      if (tid < 64){ psj = ei[nbase+tid]; pdj = ei[NE+nbase+tid]; }
    }

    // (3) tile t fully staged & visible
    __syncthreads();

    // (4) GEMM1: t1 = silu(inp @ We1 + be1)
    #pragma unroll
    for (int Mt = 0; Mt < 4; ++Mt){
      const uint32_t* arow = s_inp + (Mt*16 + lo)*ROWU + hi*4;
      f32x4 acc = {0,0,0,0};
      #pragma unroll
      for (int ks = 0; ks < 9; ++ks)
        acc = MF(*reinterpret_cast<const u32x4*>(arow + ks*16), B1[ks], acc);
      #pragma unroll
      for (int reg = 0; reg < 4; ++reg)
        t1f[((Mt*4 + ks2)*64 + SW(lp+reg))*8 + jj] = bfb(silu_f(acc[reg] + vbe1));
    }
    // issue h round A for t+1 (index arrived during GEMM1)
    if (more){
      const float* hp = h + (size_t)pnode*HD + (p8&3)*32;
      hA0 = *reinterpret_cast<const float4*>(hp);
      hA1 = *reinterpret_cast<const float4*>(hp + 4);
      hA2 = *reinterpret_cast<const float4*>(hp + 8);
      hA3 = *reinterpret_cast<const float4*>(hp + 12);
    }

    // (5) t1f ready
    __syncthreads();

    // (6) GEMM2: mij = silu(t1 @ We2 + be2); eij partials
    #pragma unroll
    for (int Mt = 0; Mt < 4; ++Mt){
      f32x4 acc = {0,0,0,0};
      #pragma unroll
      for (int ks = 0; ks < 4; ++ks)
        acc = MF(*reinterpret_cast<const u32x4*>(t1f + ((Mt*4+ks)*64 + lsw)*8), B2[ks], acc);
      float p[4];
      #pragma unroll
      for (int reg = 0; reg < 4; ++reg){
        const float m = silu_f(acc[reg] + vbe2);
        mf_[((Mt*4 + ks2)*64 + SW(lp+reg))*8 + jj] = bfb(m);
        p[reg] = m * wi;
      }
      #pragma unroll
      for (int msk = 1; msk < 16; msk <<= 1){
        #pragma unroll
        for (int reg = 0; reg < 4; ++reg) p[reg] += __shfl_xor(p[reg], msk);
      }
      if (lo == 0){
        #pragma unroll
        for (int reg = 0; reg < 4; ++reg) atomicAdd(&s_pe[Mt*16 + 4*hi + reg], p[reg]);
      }
    }
    // pack+write round A (s_inp(t) fully consumed at sync(5)); issue round B
    float4 hB0, hB1, hB2, hB3;
    if (more){
      uint32_t* dp = s_inp + r8*ROWU + p8*16;
      u32x4 vA0 = { pk2(hA0.x,hA0.y), pk2(hA0.z,hA0.w), pk2(hA1.x,hA1.y), pk2(hA1.z,hA1.w) };
      u32x4 vA1 = { pk2(hA2.x,hA2.y), pk2(hA2.z,hA2.w), pk2(hA3.x,hA3.y), pk2(hA3.z,hA3.w) };
      *reinterpret_cast<u32x4*>(dp)     = vA0;
      *reinterpret_cast<u32x4*>(dp + 4) = vA1;
      const float* hp = h + (size_t)pnode*HD + (p8&3)*32;
      hB0 = *reinterpret_cast<const float4*>(hp + 16);
      hB1 = *reinterpret_cast<const float4*>(hp + 20);
      hB2 = *reinterpret_cast<const float4*>(hp + 24);
      hB3 = *reinterpret_cast<const float4*>(hp + 28);
    }

    // (7) mf_ + s_pe ready
    __syncthreads();

    // (8a) mi scatter (reads mij back from LDS)
    #pragma unroll
    for (int Mt = 0; Mt < 4; ++Mt){
      #pragma unroll
      for (int reg = 0; reg < 4; ++reg){
        const int r = Mt*16 + 4*hi + reg;
        const float eij = sigmoid_f(s_pe[r] + vbinf);
        const float m = bf2f(mf_[((Mt*4 + ks2)*64 + SW(lp+reg))*8 + jj]);
        atomicAdd(out + (size_t)s_dst[r]*HD + col, m*eij);
      }
    }
    // (8b) GEMM3: gate partials
    #pragma unroll
    for (int Mt = 0; Mt < 4; ++Mt){
      f32x4 acc = {0,0,0,0};
      #pragma unroll
      for (int ks = 0; ks < 4; ++ks)
        acc = MF(*reinterpret_cast<const u32x4*>(mf_ + ((Mt*4+ks)*64 + lsw)*8), B3[ks], acc);
      float p[4];
      #pragma unroll
      for (int reg = 0; reg < 4; ++reg)
        p[reg] = silu_f(acc[reg] + vbx1) * wx;
      #pragma unroll
      for (int msk = 1; msk < 16; msk <<= 1){
        #pragma unroll
        for (int reg = 0; reg < 4; ++reg) p[reg] += __shfl_xor(p[reg], msk);
      }
      if (lo == 0){
        #pragma unroll
        for (int reg = 0; reg < 4; ++reg) atomicAdd(&s_pg[Mt*16 + 4*hi + reg], p[reg]);
      }
    }
    // (8c) pack+write round B; geometry prefetch + gauss write for t+1
    if (more){
      uint32_t* dp = s_inp + r8*ROWU + p8*16;
      u32x4 vB0 = { pk2(hB0.x,hB0.y), pk2(hB0.z,hB0.w), pk2(hB1.x,hB1.y), pk2(hB1.z,hB1.w) };
      u32x4 vB1 = { pk2(hB2.x,hB2.y), pk2(hB2.z,hB2.w), pk2(hB3.x,hB3.y), pk2(hB3.z,hB3.w) };
      *reinterpret_cast<u32x4*>(dp + 8)  = vB0;
      *reinterpret_cast<u32x4*>(dp + 12) = vB1;
      if (tid < 64){
        const float ax = x[pdj*3+0]-x[psj*3+0];
        const float ay = x[pdj*3+1]-x[psj*3+1];
        const float az = x[pdj*3+2]-x[psj*3+2];
        const float dd = sqrtf(ax*ax + ay*ay + az*az + 1e-8f);
        gdj = pdj; gr0 = ax; gr1 = ay; gr2 = az; gdd = dd;
        float g[24];
        #pragma unroll
        for (int j = 0; j < 20; ++j){ const float a = dd - j*SP; g[j] = __expf(CO*a*a); }
        const float4 e4 = *reinterpret_cast<const float4*>(eattr + (size_t)(nbase+tid)*EF);
        g[20]=e4.x; g[21]=e4.y; g[22]=e4.z; g[23]=e4.w;
        uint32_t* gp = s_inp + tid*ROWU + 128;
        u32x4 g0v = {pk2(g[0],g[1]),  pk2(g[2],g[3]),  pk2(g[4],g[5]),  pk2(g[6],g[7])};
        u32x4 g1v = {pk2(g[8],g[9]),  pk2(g[10],g[11]),pk2(g[12],g[13]),pk2(g[14],g[15])};
        u32x4 g2v = {pk2(g[16],g[17]),pk2(g[18],g[19]),pk2(g[20],g[21]),pk2(g[22],g[23])};
        *reinterpret_cast<u32x4*>(gp)    = g0v;
        *reinterpret_cast<u32x4*>(gp+4)  = g1v;
        *reinterpret_cast<u32x4*>(gp+8)  = g2v;
      }
    }

    // (9) s_pg ready
    __syncthreads();

    // (10) dx scatter
    if (tid < 192){
      const int er = tid/3, c = tid - 3*er;
      const float gate = tanh_f(s_pg[er]);
      const float sc = gate * fast_rcp(s_dist[er] + 1.0f);
      atomicAdd(out + (size_t)NN*HD + (size_t)s_dst[er]*3 + c, s_rel[3*er+c]*sc);
    }
  }
}

// ---------------------------------------------------------------------------
// Node kernel (MFMA): h_new = h + Wn2(silu(Wn1 [mi,h] + bn1)) + bn2, in-place
// over the mi region of out; x finalize in-place over the dx region.
// ---------------------------------------------------------------------------
#define CROW 132   // s_cat row stride in u32 (528 B = 33*16)

__global__ void __launch_bounds__(512, 4) node_kernel(
    const float* __restrict__ h, const float* __restrict__ x,
    const float* __restrict__ mask,
    const float* __restrict__ Wn1, const float* __restrict__ bn1,
    const float* __restrict__ Wn2, const float* __restrict__ bn2,
    float* __restrict__ out)
{
  __shared__ uint32_t s_cat[64*CROW];                  // 33.8 KB
  __shared__ __align__(16) uint16_t t1n[4*4*64*8];     // 16 KB

  const int tid = threadIdx.x;
  const int w = tid >> 6, l = tid & 63;
  const int lo = l & 15, hi = l >> 4;
  const int col = w*16 + lo;

  u32x4 Bn1[8], Bn2[4];
  #pragma unroll
  for (int ks = 0; ks < 8; ++ks){
    float f[8];
    #pragma unroll
    for (int j = 0; j < 8; ++j) f[j] = Wn1[(ks*32 + hi*8 + j)*HD + col];
    Bn1[ks] = {pk2(f[0],f[1]), pk2(f[2],f[3]), pk2(f[4],f[5]), pk2(f[6],f[7])};
  }
  #pragma unroll
  for (int ks = 0; ks < 4; ++ks){
    float f[8];
    #pragma unroll
    for (int j = 0; j < 8; ++j) f[j] = Wn2[(ks*32 + hi*8 + j)*HD + col];
    Bn2[ks] = {pk2(f[0],f[1]), pk2(f[2],f[3]), pk2(f[4],f[5]), pk2(f[6],f[7])};
  }
  const float vbn1 = bn1[col], vbn2 = bn2[col];
  const int nbase = blockIdx.x*64;
  const int ks2 = w >> 1;
  const int lp  = ((w&1)*2 + (lo>>3))*16 + 4*hi;
  const int jj  = lo & 7;

  {
    const int r = tid >> 3, p = tid & 7;
    const int n = nbase + r;
    uint32_t* dp = s_cat + r*CROW + p*16;
    if (n < NN){
      const float* sp = (p < 4) ? (out + (size_t)n*HD + p*32)
                                : (h   + (size_t)n*HD + (p-4)*32);
      #pragma unroll
      for (int q = 0; q < 8; ++q){
        const float4 v = *reinterpret_cast<const float4*>(sp + 4*q);
        dp[2*q]   = pk2(v.x, v.y);
        dp[2*q+1] = pk2(v.z, v.w);
      }
    } else {
      #pragma unroll
      for (int q = 0; q < 16; ++q) dp[q] = 0u;
    }
  }
  __syncthreads();

  #pragma unroll
  for (int Mt = 0; Mt < 4; ++Mt){
    const uint32_t* arow = s_cat + (Mt*16 + lo)*CROW + hi*4;
    f32x4 acc = {0,0,0,0};
    #pragma unroll
    for (int ks = 0; ks < 8; ++ks)
      acc = MF(*reinterpret_cast<const u32x4*>(arow + ks*16), Bn1[ks], acc);
    uint16_t* tp = t1n + ((Mt*4 + ks2)*64 + lp)*8 + jj;
    #pragma unroll
    for (int reg = 0; reg < 4; ++reg)
      tp[reg*8] = bfb(silu_f(acc[reg] + vbn1));
  }
  __syncthreads();

  #pragma unroll
  for (int Mt = 0; Mt < 4; ++Mt){
    f32x4 acc = {0,0,0,0};
    #pragma unroll
    for (int ks = 0; ks < 4; ++ks)
      acc = MF(*reinterpret_cast<const u32x4*>(t1n + ((Mt*4+ks)*64 + l)*8), Bn2[ks], acc);
    #pragma unroll
    for (int reg = 0; reg < 4; ++reg){
      const int n = nbase + Mt*16 + 4*hi + reg;
      if (n < NN)
        out[(size_t)n*HD + col] = h[(size_t)n*HD + col] + acc[reg] + vbn2;
    }
  }

  if (tid < 192){
    const int r = tid/3, c = tid - 3*r;
    const int n = nbase + r;
    if (n < NN){
      const size_t ix = (size_t)NN*HD + (size_t)n*3 + c;
      out[ix] = x[(size_t)n*3 + c] + out[ix]*mask[n];
    }
  }
}

extern "C" void kernel_launch(void* const* d_in, const int* in_sizes, int n_in,
                              void* d_out, int out_size, void* d_ws, size_t ws_size,
                              hipStream_t stream) {
  (void)in_sizes; (void)n_in; (void)d_ws; (void)ws_size;
  const float* h    = (const float*)d_in[0];
  const float* x    = (const float*)d_in[1];
  const int*   ei   = (const int*)  d_in[2];
  const float* mask = (const float*)d_in[3];
  const float* ea   = (const float*)d_in[4];
  const float* We1  = (const float*)d_in[5];
  const float* be1  = (const float*)d_in[6];
  const float* We2  = (const float*)d_in[7];
  const float* be2  = (const float*)d_in[8];
  const float* Winf = (const float*)d_in[9];
  const float* binf = (const float*)d_in[10];
  const float* Wx1  = (const float*)d_in[11];
  const float* bx1  = (const float*)d_in[12];
  const float* Wx2  = (const float*)d_in[13];
  const float* Wn1  = (const float*)d_in[14];
  const float* bn1  = (const float*)d_in[15];
  const float* Wn2  = (const float*)d_in[16];
  const float* bn2  = (const float*)d_in[17];
  float* out = (float*)d_out;

  hipFuncSetAttribute(reinterpret_cast<const void*>(edge_kernel),
                      hipFuncAttributeMaxDynamicSharedMemorySize, EDGE_LDS_B);

  // out[0..NN*HD) accumulates mi; out[NN*HD..) accumulates delta_x
  hipMemsetAsync(d_out, 0, (size_t)out_size * sizeof(float), stream);

  edge_kernel<<<EGRID, 512, EDGE_LDS_B, stream>>>(
      h, x, ei, ea, We1, be1, We2, be2, Winf, binf, Wx1, bx1, Wx2, out);
  node_kernel<<<NTILE, 512, 0, stream>>>(
      h, x, mask, Wn1, bn1, Wn2, bn2, out);
}

// Round 6
// 459.339 us; speedup vs baseline: 1.6475x; 1.6475x over previous
//
#include <hip/hip_runtime.h>
#include <hip/hip_bf16.h>
#include <cstdint>

// Problem constants (EnBaseLayer: E(n)-GNN layer)
#define NN 50000
#define NE 600000
#define HD 128
#define NG 20
#define EF 4
#define K1 280            // 2H + NG + EF
#define TILES (NE/64)     // 9375
#define EGRID 512         // 2 blocks/CU resident
#define ROWU 148          // s_inp row stride in u32 (592 B = 37*16)
#define NTILE 782         // ceil(NN/64)
// bank-conflict swizzle: permute 16B slots within each 8-row (128B) group
#define SW(r) ((r) ^ (((r)>>3)&7))

typedef __attribute__((ext_vector_type(4))) float f32x4;
typedef __attribute__((ext_vector_type(8))) __bf16 bf16x8;
typedef __attribute__((ext_vector_type(4))) unsigned int u32x4;

__device__ __forceinline__ float fast_rcp(float x){ return __builtin_amdgcn_rcpf(x); }
__device__ __forceinline__ float silu_f(float x){ return x * fast_rcp(1.0f + __expf(-x)); }
__device__ __forceinline__ float sigmoid_f(float x){ return fast_rcp(1.0f + __expf(-x)); }
__device__ __forceinline__ float tanh_f(float x){ return 1.0f - 2.0f*fast_rcp(__expf(2.0f*x)+1.0f); }

__device__ __forceinline__ uint32_t pk2(float a, float b){   // RNE f32x2 -> bf16x2
  uint32_t ua = __float_as_uint(a); ua += 0x7FFFu + ((ua>>16)&1u);
  uint32_t ub = __float_as_uint(b); ub += 0x7FFFu + ((ub>>16)&1u);
  return (ua>>16) | (ub & 0xFFFF0000u);
}
__device__ __forceinline__ uint16_t bfb(float a){
  uint32_t ua = __float_as_uint(a); ua += 0x7FFFu + ((ua>>16)&1u);
  return (uint16_t)(ua>>16);
}
__device__ __forceinline__ float bf2f(uint16_t b){ return __uint_as_float(((uint32_t)b)<<16); }
__device__ __forceinline__ f32x4 MF(u32x4 a, u32x4 b, f32x4 c){
  return __builtin_amdgcn_mfma_f32_16x16x32_bf16(
      __builtin_bit_cast(bf16x8, a), __builtin_bit_cast(bf16x8, b), c, 0, 0, 0);
}

#define EDGE_LDS_U32 (64*ROWU + 4096 + 4096 + 448)
#define EDGE_LDS_B (EDGE_LDS_U32*4)   // 72448 B -> 2 blocks/CU

// ---------------------------------------------------------------------------
// h -> bf16 copy (halves gather bytes for the edge kernel).
// 6.4M elems, 8 per thread, grid exact: 800000 threads = 3125*256.
// ---------------------------------------------------------------------------
__global__ void __launch_bounds__(256) h2bf_kernel(
    const float* __restrict__ h, uint32_t* __restrict__ hb)
{
  const size_t i = ((size_t)blockIdx.x*256 + threadIdx.x)*8;
  const float4 a = *reinterpret_cast<const float4*>(h + i);
  const float4 b = *reinterpret_cast<const float4*>(h + i + 4);
  u32x4 v = {pk2(a.x,a.y), pk2(a.z,a.w), pk2(b.x,b.y), pk2(b.z,b.w)};
  *reinterpret_cast<u32x4*>(hb + i/2) = v;
}

// ---------------------------------------------------------------------------
// Edge kernel (round-3 structure + bf16-h gather + index-only prefetch).
// 8 waves/block, tile = 64 edges. Wave w owns N-tile w (channels 16w..16w+15).
// A-frag: lane l holds row l&15, k = 32ks + 8*(l>>4) + j.
// D-frag: row(m)=4*(l>>4)+reg, col(n)=l&15.
// t1f/mf_ slot index XOR-swizzled (SW).
// Cross-iteration state: 3 ints (edge indices for t+1) -- no spill risk.
// ---------------------------------------------------------------------------
template<int BF16H>
__global__ void __launch_bounds__(512, 4) edge_kernel(
    const float* __restrict__ h, const uint32_t* __restrict__ hb,
    const float* __restrict__ x,
    const int* __restrict__ ei, const float* __restrict__ eattr,
    const float* __restrict__ We1, const float* __restrict__ be1,
    const float* __restrict__ We2, const float* __restrict__ be2,
    const float* __restrict__ Winf, const float* __restrict__ binf,
    const float* __restrict__ Wx1, const float* __restrict__ bx1,
    const float* __restrict__ Wx2, float* __restrict__ out)
{
  extern __shared__ uint32_t smem[];
  uint32_t* s_inp = smem;                                   // [64][ROWU]
  uint16_t* t1f   = (uint16_t*)(smem + 64*ROWU);            // [16][64][8] u16
  uint16_t* mf_   = (uint16_t*)(smem + 64*ROWU + 4096);     // [16][64][8] u16
  uint32_t* tl    = smem + 64*ROWU + 8192;
  int*   s_dst  = (int*)tl;            // 64
  float* s_rel  = (float*)(tl+64);     // 192
  float* s_dist = (float*)(tl+256);    // 64
  float* s_pe   = (float*)(tl+320);    // 64
  float* s_pg   = (float*)(tl+384);    // 64

  const int tid = threadIdx.x;
  const int w = tid >> 6, l = tid & 63;
  const int lo = l & 15, hi = l >> 4;
  const int col = w*16 + lo;
  const int r8 = tid >> 3, p8 = tid & 7;
  const int ks2 = w >> 1;
  const int lp  = ((w&1)*2 + (lo>>3))*16 + 4*hi;
  const int jj  = lo & 7;
  const int lsw = SW(l);

  // ---- persistent weight B-fragments (17 frags = 68 regs) ----
  u32x4 B1[9], B2[4], B3[4];
  #pragma unroll
  for (int ks = 0; ks < 9; ++ks){
    float f[8];
    #pragma unroll
    for (int j = 0; j < 8; ++j){
      const int k = ks*32 + hi*8 + j;
      f[j] = (k < K1) ? We1[k*HD + col] : 0.0f;
    }
    B1[ks] = {pk2(f[0],f[1]), pk2(f[2],f[3]), pk2(f[4],f[5]), pk2(f[6],f[7])};
  }
  #pragma unroll
  for (int ks = 0; ks < 4; ++ks){
    float f2[8], f3[8];
    #pragma unroll
    for (int j = 0; j < 8; ++j){
      const int k = ks*32 + hi*8 + j;
      f2[j] = We2[k*HD + col];
      f3[j] = Wx1[k*HD + col];
    }
    B2[ks] = {pk2(f2[0],f2[1]), pk2(f2[2],f2[3]), pk2(f2[4],f2[5]), pk2(f2[6],f2[7])};
    B3[ks] = {pk2(f3[0],f3[1]), pk2(f3[2],f3[3]), pk2(f3[4],f3[5]), pk2(f3[6],f3[7])};
  }
  const float vbe1 = be1[col], vbe2 = be2[col], vbx1 = bx1[col];
  const float wi = Winf[col], wx = Wx2[col], vbinf = binf[0];
  const float SP = 10.0f/19.0f;
  const float CO = -0.5f/(SP*SP);

  // ---- cross-iteration state: edge indices for tile t (3 ints) ----
  int pnode, psj = 0, pdj = 0;
  {
    const int ebase = blockIdx.x*64;
    pnode = (p8 < 4) ? ei[NE + ebase + r8] : ei[ebase + r8];
    if (tid < 64){ psj = ei[ebase + tid]; pdj = ei[NE + ebase + tid]; }
  }

  for (int t = blockIdx.x; t < TILES; t += EGRID){
    const int ebase = t*64;
    __syncthreads();                         // prior tile fully consumed

    // ---- phase A (tid<64): geometry, gauss+attr cols, zero partials ----
    if (tid < 64){
      const float ax = x[pdj*3+0]-x[psj*3+0];
      const float ay = x[pdj*3+1]-x[psj*3+1];
      const float az = x[pdj*3+2]-x[psj*3+2];
      const float dd = sqrtf(ax*ax + ay*ay + az*az + 1e-8f);
      s_dst[tid] = pdj;
      s_rel[3*tid+0]=ax; s_rel[3*tid+1]=ay; s_rel[3*tid+2]=az;
      s_dist[tid]=dd; s_pe[tid]=0.0f; s_pg[tid]=0.0f;
      float g[24];
      #pragma unroll
      for (int j = 0; j < 20; ++j){ const float a = dd - j*SP; g[j] = __expf(CO*a*a); }
      const float4 e4 = *reinterpret_cast<const float4*>(eattr + (size_t)(ebase+tid)*EF);
      g[20]=e4.x; g[21]=e4.y; g[22]=e4.z; g[23]=e4.w;
      uint32_t* gp = s_inp + tid*ROWU + 128;
      u32x4 g0v = {pk2(g[0],g[1]),  pk2(g[2],g[3]),  pk2(g[4],g[5]),  pk2(g[6],g[7])};
      u32x4 g1v = {pk2(g[8],g[9]),  pk2(g[10],g[11]),pk2(g[12],g[13]),pk2(g[14],g[15])};
      u32x4 g2v = {pk2(g[16],g[17]),pk2(g[18],g[19]),pk2(g[20],g[21]),pk2(g[22],g[23])};
      u32x4 g3v = {0,0,0,0};
      *reinterpret_cast<u32x4*>(gp)    = g0v;
      *reinterpret_cast<u32x4*>(gp+4)  = g1v;
      *reinterpret_cast<u32x4*>(gp+8)  = g2v;
      *reinterpret_cast<u32x4*>(gp+12) = g3v;
    }
    // ---- phase B (all threads): gather h row chunk (address ready!) ----
    if (BF16H){
      const uint32_t* hw = hb + (size_t)pnode*(HD/2) + (p8&3)*16;
      uint32_t* dp = s_inp + r8*ROWU + p8*16;
      #pragma unroll
      for (int q = 0; q < 4; ++q)
        *reinterpret_cast<u32x4*>(dp + 4*q) = *reinterpret_cast<const u32x4*>(hw + 4*q);
    } else {
      const float* hp = h + (size_t)pnode*HD + (p8&3)*32;
      uint32_t* dp = s_inp + r8*ROWU + p8*16;
      #pragma unroll
      for (int q = 0; q < 4; ++q){
        const float4 va = *reinterpret_cast<const float4*>(hp + 8*q);
        const float4 vb = *reinterpret_cast<const float4*>(hp + 8*q + 4);
        u32x4 v = { pk2(va.x,va.y), pk2(va.z,va.w), pk2(vb.x,vb.y), pk2(vb.z,vb.w) };
        *reinterpret_cast<u32x4*>(dp + 4*q) = v;
      }
    }
    // ---- prefetch t+1 indices (3 ints; loads drain during GEMMs) ----
    int np = pnode, ns = psj, nd = pdj;
    if (t + EGRID < TILES){
      const int nb = (t + EGRID)*64;
      np = (p8 < 4) ? ei[NE + nb + r8] : ei[nb + r8];
      if (tid < 64){ ns = ei[nb + tid]; nd = ei[NE + nb + tid]; }
    }
    __syncthreads();

    // ---------------- GEMM1: t1 = silu(inp @ We1 + be1) ----------------
    #pragma unroll
    for (int Mt = 0; Mt < 4; ++Mt){
      const uint32_t* arow = s_inp + (Mt*16 + lo)*ROWU + hi*4;
      f32x4 acc = {0,0,0,0};
      #pragma unroll
      for (int ks = 0; ks < 9; ++ks)
        acc = MF(*reinterpret_cast<const u32x4*>(arow + ks*16), B1[ks], acc);
      #pragma unroll
      for (int reg = 0; reg < 4; ++reg)
        t1f[((Mt*4 + ks2)*64 + SW(lp+reg))*8 + jj] = bfb(silu_f(acc[reg] + vbe1));
    }
    __syncthreads();

    // ---------------- GEMM2: mij = silu(t1 @ We2 + be2); eij partials ----
    #pragma unroll
    for (int Mt = 0; Mt < 4; ++Mt){
      f32x4 acc = {0,0,0,0};
      #pragma unroll
      for (int ks = 0; ks < 4; ++ks)
        acc = MF(*reinterpret_cast<const u32x4*>(t1f + ((Mt*4+ks)*64 + lsw)*8), B2[ks], acc);
      float p[4];
      #pragma unroll
      for (int reg = 0; reg < 4; ++reg){
        const float m = silu_f(acc[reg] + vbe2);
        mf_[((Mt*4 + ks2)*64 + SW(lp+reg))*8 + jj] = bfb(m);
        p[reg] = m * wi;
      }
      #pragma unroll
      for (int msk = 1; msk < 16; msk <<= 1){
        #pragma unroll
        for (int reg = 0; reg < 4; ++reg) p[reg] += __shfl_xor(p[reg], msk);
      }
      if (lo == 0){
        #pragma unroll
        for (int reg = 0; reg < 4; ++reg) atomicAdd(&s_pe[Mt*16 + 4*hi + reg], p[reg]);
      }
    }
    __syncthreads();

    // ---------------- mi scatter (reads mij back from LDS) ----------------
    #pragma unroll
    for (int Mt = 0; Mt < 4; ++Mt){
      #pragma unroll
      for (int reg = 0; reg < 4; ++reg){
        const int r = Mt*16 + 4*hi + reg;
        const float eij = sigmoid_f(s_pe[r] + vbinf);
        const float m = bf2f(mf_[((Mt*4 + ks2)*64 + SW(lp+reg))*8 + jj]);
        atomicAdd(out + (size_t)s_dst[r]*HD + col, m*eij);
      }
    }
    // ---------------- GEMM3: gate partials ----------------
    #pragma unroll
    for (int Mt = 0; Mt < 4; ++Mt){
      f32x4 acc = {0,0,0,0};
      #pragma unroll
      for (int ks = 0; ks < 4; ++ks)
        acc = MF(*reinterpret_cast<const u32x4*>(mf_ + ((Mt*4+ks)*64 + lsw)*8), B3[ks], acc);
      float p[4];
      #pragma unroll
      for (int reg = 0; reg < 4; ++reg)
        p[reg] = silu_f(acc[reg] + vbx1) * wx;
      #pragma unroll
      for (int msk = 1; msk < 16; msk <<= 1){
        #pragma unroll
        for (int reg = 0; reg < 4; ++reg) p[reg] += __shfl_xor(p[reg], msk);
      }
      if (lo == 0){
        #pragma unroll
        for (int reg = 0; reg < 4; ++reg) atomicAdd(&s_pg[Mt*16 + 4*hi + reg], p[reg]);
      }
    }
    __syncthreads();

    // ---------------- dx scatter ----------------
    if (tid < 192){
      const int er = tid/3, c = tid - 3*er;
      const float gate = tanh_f(s_pg[er]);
      const float sc = gate * fast_rcp(s_dist[er] + 1.0f);
      atomicAdd(out + (size_t)NN*HD + (size_t)s_dst[er]*3 + c, s_rel[3*er+c]*sc);
    }

    pnode = np; psj = ns; pdj = nd;
  }
}

// ---------------------------------------------------------------------------
// Node kernel (MFMA): h_new = h + Wn2(silu(Wn1 [mi,h] + bn1)) + bn2, in-place
// over the mi region of out; x finalize in-place over the dx region.
// ---------------------------------------------------------------------------
#define CROW 132   // s_cat row stride in u32 (528 B = 33*16)

__global__ void __launch_bounds__(512, 4) node_kernel(
    const float* __restrict__ h, const float* __restrict__ x,
    const float* __restrict__ mask,
    const float* __restrict__ Wn1, const float* __restrict__ bn1,
    const float* __restrict__ Wn2, const float* __restrict__ bn2,
    float* __restrict__ out)
{
  __shared__ uint32_t s_cat[64*CROW];                  // 33.8 KB
  __shared__ __align__(16) uint16_t t1n[4*4*64*8];     // 16 KB

  const int tid = threadIdx.x;
  const int w = tid >> 6, l = tid & 63;
  const int lo = l & 15, hi = l >> 4;
  const int col = w*16 + lo;

  u32x4 Bn1[8], Bn2[4];
  #pragma unroll
  for (int ks = 0; ks < 8; ++ks){
    float f[8];
    #pragma unroll
    for (int j = 0; j < 8; ++j) f[j] = Wn1[(ks*32 + hi*8 + j)*HD + col];
    Bn1[ks] = {pk2(f[0],f[1]), pk2(f[2],f[3]), pk2(f[4],f[5]), pk2(f[6],f[7])};
  }
  #pragma unroll
  for (int ks = 0; ks < 4; ++ks){
    float f[8];
    #pragma unroll
    for (int j = 0; j < 8; ++j) f[j] = Wn2[(ks*32 + hi*8 + j)*HD + col];
    Bn2[ks] = {pk2(f[0],f[1]), pk2(f[2],f[3]), pk2(f[4],f[5]), pk2(f[6],f[7])};
  }
  const float vbn1 = bn1[col], vbn2 = bn2[col];
  const int nbase = blockIdx.x*64;
  const int ks2 = w >> 1;
  const int lp  = ((w&1)*2 + (lo>>3))*16 + 4*hi;
  const int jj  = lo & 7;

  {
    const int r = tid >> 3, p = tid & 7;
    const int n = nbase + r;
    uint32_t* dp = s_cat + r*CROW + p*16;
    if (n < NN){
      const float* sp = (p < 4) ? (out + (size_t)n*HD + p*32)
                                : (h   + (size_t)n*HD + (p-4)*32);
      #pragma unroll
      for (int q = 0; q < 8; ++q){
        const float4 v = *reinterpret_cast<const float4*>(sp + 4*q);
        dp[2*q]   = pk2(v.x, v.y);
        dp[2*q+1] = pk2(v.z, v.w);
      }
    } else {
      #pragma unroll
      for (int q = 0; q < 16; ++q) dp[q] = 0u;
    }
  }
  __syncthreads();

  #pragma unroll
  for (int Mt = 0; Mt < 4; ++Mt){
    const uint32_t* arow = s_cat + (Mt*16 + lo)*CROW + hi*4;
    f32x4 acc = {0,0,0,0};
    #pragma unroll
    for (int ks = 0; ks < 8; ++ks)
      acc = MF(*reinterpret_cast<const u32x4*>(arow + ks*16), Bn1[ks], acc);
    uint16_t* tp = t1n + ((Mt*4 + ks2)*64 + lp)*8 + jj;
    #pragma unroll
    for (int reg = 0; reg < 4; ++reg)
      tp[reg*8] = bfb(silu_f(acc[reg] + vbn1));
  }
  __syncthreads();

  #pragma unroll
  for (int Mt = 0; Mt < 4; ++Mt){
    f32x4 acc = {0,0,0,0};
    #pragma unroll
    for (int ks = 0; ks < 4; ++ks)
      acc = MF(*reinterpret_cast<const u32x4*>(t1n + ((Mt*4+ks)*64 + l)*8), Bn2[ks], acc);
    #pragma unroll
    for (int reg = 0; reg < 4; ++reg){
      const int n = nbase + Mt*16 + 4*hi + reg;
      if (n < NN)
        out[(size_t)n*HD + col] = h[(size_t)n*HD + col] + acc[reg] + vbn2;
    }
  }

  if (tid < 192){
    const int r = tid/3, c = tid - 3*r;
    const int n = nbase + r;
    if (n < NN){
      const size_t ix = (size_t)NN*HD + (size_t)n*3 + c;
      out[ix] = x[(size_t)n*3 + c] + out[ix]*mask[n];
    }
  }
}

extern "C" void kernel_launch(void* const* d_in, const int* in_sizes, int n_in,
                              void* d_out, int out_size, void* d_ws, size_t ws_size,
                              hipStream_t stream) {
  (void)in_sizes; (void)n_in;
  const float* h    = (const float*)d_in[0];
  const float* x    = (const float*)d_in[1];
  const int*   ei   = (const int*)  d_in[2];
  const float* mask = (const float*)d_in[3];
  const float* ea   = (const float*)d_in[4];
  const float* We1  = (const float*)d_in[5];
  const float* be1  = (const float*)d_in[6];
  const float* We2  = (const float*)d_in[7];
  const float* be2  = (const float*)d_in[8];
  const float* Winf = (const float*)d_in[9];
  const float* binf = (const float*)d_in[10];
  const float* Wx1  = (const float*)d_in[11];
  const float* bx1  = (const float*)d_in[12];
  const float* Wx2  = (const float*)d_in[13];
  const float* Wn1  = (const float*)d_in[14];
  const float* bn1  = (const float*)d_in[15];
  const float* Wn2  = (const float*)d_in[16];
  const float* bn2  = (const float*)d_in[17];
  float* out = (float*)d_out;

  const bool use_bf = ws_size >= (size_t)NN*HD*2;
  uint32_t* hb = (uint32_t*)d_ws;

  hipFuncSetAttribute(reinterpret_cast<const void*>(edge_kernel<1>),
                      hipFuncAttributeMaxDynamicSharedMemorySize, EDGE_LDS_B);
  hipFuncSetAttribute(reinterpret_cast<const void*>(edge_kernel<0>),
                      hipFuncAttributeMaxDynamicSharedMemorySize, EDGE_LDS_B);

  // out[0..NN*HD) accumulates mi; out[NN*HD..) accumulates delta_x
  hipMemsetAsync(d_out, 0, (size_t)out_size * sizeof(float), stream);

  if (use_bf){
    h2bf_kernel<<<3125, 256, 0, stream>>>(h, hb);
    edge_kernel<1><<<EGRID, 512, EDGE_LDS_B, stream>>>(
        h, hb, x, ei, ea, We1, be1, We2, be2, Winf, binf, Wx1, bx1, Wx2, out);
  } else {
    edge_kernel<0><<<EGRID, 512, EDGE_LDS_B, stream>>>(
        h, hb, x, ei, ea, We1, be1, We2, be2, Winf, binf, Wx1, bx1, Wx2, out);
  }
  node_kernel<<<NTILE, 512, 0, stream>>>(
      h, x, mask, Wn1, bn1, Wn2, bn2, out);
}